// Round 4
// baseline (46.834 us; speedup 1.0000x reference)
//
#include <hip/hip_runtime.h>

#define NROWS 32768
#define DDIM  512
#define NF4   (DDIM / 4)      // 128 float4 per row
#define WGS   512             // workgroups (2 per CU, whole grid co-resident)
#define TPB   512             // 8 waves per workgroup
#define RPW   8               // rows per wave: 512*8*8 = 32768

struct RowBuf { float4 A0, A1, B0, B1, C0, C1, D0, D1; };

__device__ __forceinline__ void load_row(RowBuf& R,
    const float4* __restrict__ ibase, const float4* __restrict__ abase,
    int row, int ii, int ai, int lane)
{
    const float4* pR = ibase + (size_t)row * NF4 + lane;
    const float4* qR = abase + (size_t)row * NF4 + lane;
    const float4* pI = ibase + (size_t)ii  * NF4 + lane;
    const float4* qA = abase + (size_t)ai  * NF4 + lane;
    R.A0 = pR[0]; R.A1 = pR[64];
    R.B0 = qR[0]; R.B1 = qR[64];
    R.C0 = pI[0]; R.C1 = pI[64];
    R.D0 = qA[0]; R.D1 = qA[64];
}

__device__ __forceinline__ float row_loss(const RowBuf& R)
{
    // u = (img[ii]-img[row]).aud[row] = Iimpsim - anchorsim
    // v = img[row].(aud[ai]-aud[row]) = Aimpsim - anchorsim
    float u = (R.C0.x - R.A0.x) * R.B0.x + (R.C0.y - R.A0.y) * R.B0.y
            + (R.C0.z - R.A0.z) * R.B0.z + (R.C0.w - R.A0.w) * R.B0.w
            + (R.C1.x - R.A1.x) * R.B1.x + (R.C1.y - R.A1.y) * R.B1.y
            + (R.C1.z - R.A1.z) * R.B1.z + (R.C1.w - R.A1.w) * R.B1.w;
    float v = R.A0.x * (R.D0.x - R.B0.x) + R.A0.y * (R.D0.y - R.B0.y)
            + R.A0.z * (R.D0.z - R.B0.z) + R.A0.w * (R.D0.w - R.B0.w)
            + R.A1.x * (R.D1.x - R.B1.x) + R.A1.y * (R.D1.y - R.B1.y)
            + R.A1.z * (R.D1.z - R.B1.z) + R.A1.w * (R.D1.w - R.B1.w);
    #pragma unroll
    for (int off = 1; off < 64; off <<= 1) {
        u += __shfl_xor(u, off, 64);
        v += __shfl_xor(v, off, 64);
    }
    return fmaxf(0.f, 1.f + u) + fmaxf(0.f, 1.f + v);
}

__global__ __launch_bounds__(TPB, 4) void dotloss_main(
    const float* __restrict__ img,
    const float* __restrict__ aud,
    const int*   __restrict__ iimp,
    const int*   __restrict__ aimp,
    float* __restrict__ partial)
{
    const int lane = threadIdx.x & 63;
    const int wave = threadIdx.x >> 6;            // 0..7
    const int gw   = (blockIdx.x << 3) + wave;    // global wave 0..4095
    const int row0 = gw * RPW;

    const float4* ibase = (const float4*)img;
    const float4* abase = (const float4*)aud;

    RowBuf X, Y;
    float acc = 0.f;

    {
        int ii = iimp[row0], ai = aimp[row0];
        load_row(X, ibase, abase, row0, ii, ai, lane);
    }

    #pragma unroll
    for (int r = 0; r < RPW; r += 2) {
        // issue row r+1 loads (buffer Y) before consuming X
        {
            int r1 = row0 + r + 1;
            int i1 = iimp[r1], a1 = aimp[r1];
            load_row(Y, ibase, abase, r1, i1, a1, lane);
        }
        acc += row_loss(X);
        // issue row r+2 loads (buffer X) before consuming Y
        if (r + 2 < RPW) {
            int r2 = row0 + r + 2;
            int i2 = iimp[r2], a2 = aimp[r2];
            load_row(X, ibase, abase, r2, i2, a2, lane);
        }
        acc += row_loss(Y);
    }

    __shared__ float s[TPB / 64];
    if (lane == 0) s[wave] = acc;
    __syncthreads();
    if (threadIdx.x == 0) {
        float t = 0.f;
        #pragma unroll
        for (int w = 0; w < TPB / 64; ++w) t += s[w];
        partial[blockIdx.x] = t;
    }
}

__global__ __launch_bounds__(256) void dotloss_reduce(
    const float* __restrict__ partial,
    float* __restrict__ out)
{
    const int tid = threadIdx.x;
    float t = partial[tid] + partial[tid + 256];   // WGS=512 partials

    #pragma unroll
    for (int off = 32; off > 0; off >>= 1) t += __shfl_xor(t, off, 64);

    __shared__ float s[4];
    if ((tid & 63) == 0) s[tid >> 6] = t;
    __syncthreads();
    if (tid == 0) out[0] = (s[0] + s[1] + s[2] + s[3]) * (1.0f / (float)NROWS);
}

extern "C" void kernel_launch(void* const* d_in, const int* in_sizes, int n_in,
                              void* d_out, int out_size, void* d_ws, size_t ws_size,
                              hipStream_t stream) {
    const float* img  = (const float*)d_in[0];
    const float* aud  = (const float*)d_in[1];
    const int*   iimp = (const int*)d_in[2];
    const int*   aimp = (const int*)d_in[3];
    float* out     = (float*)d_out;
    float* partial = (float*)d_ws;   // 512 floats

    dotloss_main<<<WGS, TPB, 0, stream>>>(img, aud, iimp, aimp, partial);
    dotloss_reduce<<<1, 256, 0, stream>>>(partial, out);
}

// Round 5
// 43.884 us; speedup vs baseline: 1.0672x; 1.0672x over previous
//
#include <hip/hip_runtime.h>

#define NROWS  32768
#define DDIM   512
#define NF4    (DDIM / 4)   // 128 float4 per row
#define BLOCKS 2048         // 16 rows per block

// 16 lanes per row; 16 rows per 256-thread block.
// All 32 float4 loads per lane are issued before any use (max MLP).
__global__ __launch_bounds__(256) void dotloss_main(
    const float* __restrict__ img,
    const float* __restrict__ aud,
    const int*   __restrict__ iimp,
    const int*   __restrict__ aimp,
    float* __restrict__ partial)
{
    const int tid = threadIdx.x;
    const int g   = tid & 15;            // lane within 16-lane row group
    const int grp = tid >> 4;            // row group within block
    const int row = (blockIdx.x << 4) + grp;

    const int ii = iimp[row];
    const int ai = aimp[row];

    const float4* __restrict__ pR = (const float4*)(img) + (size_t)row * NF4 + g;
    const float4* __restrict__ qR = (const float4*)(aud) + (size_t)row * NF4 + g;
    const float4* __restrict__ pI = (const float4*)(img) + (size_t)ii  * NF4 + g;
    const float4* __restrict__ qA = (const float4*)(aud) + (size_t)ai  * NF4 + g;

    // Issue everything: 32 independent float4 loads per lane.
    float4 a[8], b[8], c[8], d[8];
    #pragma unroll
    for (int k = 0; k < 8; ++k) a[k] = pR[16 * k];
    #pragma unroll
    for (int k = 0; k < 8; ++k) b[k] = qR[16 * k];
    #pragma unroll
    for (int k = 0; k < 8; ++k) c[k] = pI[16 * k];
    #pragma unroll
    for (int k = 0; k < 8; ++k) d[k] = qA[16 * k];

    // u = (img[ii]-img[row]).aud[row] = Iimpsim - anchorsim
    // v = img[row].(aud[ai]-aud[row]) = Aimpsim - anchorsim
    float u0 = 0.f, u1 = 0.f, v0 = 0.f, v1 = 0.f;
    #pragma unroll
    for (int k = 0; k < 8; ++k) {
        u0 += (c[k].x - a[k].x) * b[k].x + (c[k].y - a[k].y) * b[k].y;
        u1 += (c[k].z - a[k].z) * b[k].z + (c[k].w - a[k].w) * b[k].w;
        v0 += a[k].x * (d[k].x - b[k].x) + a[k].y * (d[k].y - b[k].y);
        v1 += a[k].z * (d[k].z - b[k].z) + a[k].w * (d[k].w - b[k].w);
    }
    float u = u0 + u1;
    float v = v0 + v1;

    #pragma unroll
    for (int off = 1; off < 16; off <<= 1) {
        u += __shfl_xor(u, off, 64);
        v += __shfl_xor(v, off, 64);
    }

    float loss = fmaxf(0.f, 1.f + u) + fmaxf(0.f, 1.f + v);

    __shared__ float s[16];
    if (g == 0) s[grp] = loss;
    __syncthreads();
    if (tid == 0) {
        float t = 0.f;
        #pragma unroll
        for (int i = 0; i < 16; ++i) t += s[i];
        partial[blockIdx.x] = t;   // plain store, no atomic
    }
}

__global__ __launch_bounds__(256) void dotloss_reduce(
    const float* __restrict__ partial,
    float* __restrict__ out)
{
    const int tid = threadIdx.x;
    float t = 0.f;
    #pragma unroll
    for (int k = 0; k < BLOCKS / 256; ++k) t += partial[tid + 256 * k];

    #pragma unroll
    for (int off = 32; off > 0; off >>= 1) t += __shfl_xor(t, off, 64);

    __shared__ float s[4];
    if ((tid & 63) == 0) s[tid >> 6] = t;
    __syncthreads();
    if (tid == 0) out[0] = (s[0] + s[1] + s[2] + s[3]) * (1.0f / (float)NROWS);
}

extern "C" void kernel_launch(void* const* d_in, const int* in_sizes, int n_in,
                              void* d_out, int out_size, void* d_ws, size_t ws_size,
                              hipStream_t stream) {
    const float* img  = (const float*)d_in[0];
    const float* aud  = (const float*)d_in[1];
    const int*   iimp = (const int*)d_in[2];
    const int*   aimp = (const int*)d_in[3];
    float* out     = (float*)d_out;
    float* partial = (float*)d_ws;   // 2048 floats = 8 KB scratch

    dotloss_main<<<BLOCKS, 256, 0, stream>>>(img, aud, iimp, aimp, partial);
    dotloss_reduce<<<1, 256, 0, stream>>>(partial, out);
}